// Round 5
// baseline (78.644 us; speedup 1.0000x reference)
//
#include <hip/hip_runtime.h>

#define SENT (-3.402823466e38f)

__device__ __forceinline__ float dot4(float4 a, float4 b) {
    return a.x*b.x + a.y*b.y + a.z*b.z + a.w*b.w;
}

__device__ __forceinline__ float wred(float v) {
    #pragma unroll
    for (int off = 32; off >= 1; off >>= 1) v += __shfl_xor(v, off);
    return v;
}

// One block per 2 rows (b,i): 256 blocks x 1024 threads (16 waves).
// All weight reads are full-row coalesced (lane-over-K + butterfly reduce).
// Attention phases: one wave per (row, head), no internal barriers.
__global__ __launch_bounds__(1024, 4)
void fused_all(const float* __restrict__ x, const int* __restrict__ msk,
               const float* __restrict__ edge,
               const float* __restrict__ Wq, const float* __restrict__ bq,
               const float* __restrict__ Wk,
               const float* __restrict__ Wv, const float* __restrict__ bv,
               const float* __restrict__ Wp, const float* __restrict__ bp,
               float* __restrict__ out) {
    __shared__ float eds[2][128*68];   // edge rows, stride 68 (16B-aligned)
    __shared__ float xL[2][256];
    __shared__ float qls[2][256];      // q = Wq x + bq
    __shared__ float vnodeL[2][256];   // Wv_node x + bv
    __shared__ float qkpL[2][512];     // (q^T Wk_edge)/sqrt(D), [h][e]
    __shared__ float mval[2][128];
    __shared__ float attL[2][8*132];   // softmax weights, stride 132
    __shared__ float aggF[2][512];     // [h][e]
    __shared__ float yL[2][256];

    int tid = threadIdx.x;
    int wv = tid >> 6, lane = tid & 63;
    int rA = blockIdx.x * 2;

    // issue edge loads (both rows) into regs; latency hides under proj loop
    float4 ef[4];
    {
        const float* eg = edge + (size_t)rA * 8192;
        #pragma unroll
        for (int it = 0; it < 4; ++it)
            ef[it] = *(const float4*)(eg + (size_t)(tid + 1024*it)*4);
    }

    if (tid < 512) {            // x rows
        int r = tid >> 8, c = tid & 255;
        xL[r][c] = x[(size_t)(rA + r)*256 + c];
    } else if (tid < 768) {     // mask
        int idx = tid - 512;
        int r = idx >> 7, j = idx & 127;
        mval[r][j] = (msk[(size_t)(rA + r)*128 + j] != 0) ? 1.0f : 0.0f;
    }
    __syncthreads();

    {   // P1: q (waves 0-7) / v_node (waves 8-15) projections, both rows.
        // Wave reads one full weight row per iter (coalesced 1KB), dots
        // against both x rows, butterfly-reduces.
        float4 xa = *(float4*)&xL[0][lane*4];
        float4 xb = *(float4*)&xL[1][lane*4];
        bool isQ = (wv < 8);
        int w8 = wv & 7;
        const float* Wsrc = isQ ? Wq : Wv;
        int wstride = isQ ? 256 : 320;
        const float* bsrc = isQ ? bq : bv;
        float* dst0 = isQ ? qls[0] : vnodeL[0];
        float* dst1 = isQ ? qls[1] : vnodeL[1];
        #pragma unroll 4
        for (int it = 0; it < 32; ++it) {
            int c = it*8 + w8;
            float4 w4 = *(const float4*)&Wsrc[(size_t)c*wstride + lane*4];
            float d0 = wred(dot4(w4, xa));
            float d1 = wred(dot4(w4, xb));
            if (lane == 0) {
                float bb = bsrc[c];
                dst0[c] = d0 + bb;
                dst1[c] = d1 + bb;
            }
        }
        // stage edge regs -> LDS (global loads long arrived)
        #pragma unroll
        for (int it = 0; it < 4; ++it) {
            int f = tid + 1024*it;
            int r = f >> 11, fr = f & 2047, j = fr >> 4, e4 = fr & 15;
            *(float4*)&eds[r][j*68 + e4*4] = ef[it];
        }
    }
    __syncthreads();

    if (wv < 8) {   // P2: qkp for both rows; wave = head, lane = e (coalesced)
        int h = wv;
        const float* wkp = Wk + (size_t)(h*32)*320 + 256 + lane;
        float a0 = 0.f, a1 = 0.f;
        #pragma unroll 8
        for (int d = 0; d < 32; ++d) {
            float w = wkp[(size_t)d*320];
            a0 += qls[0][h*32 + d] * w;   // wave-uniform broadcast
            a1 += qls[1][h*32 + d] * w;
        }
        qkpL[0][h*64 + lane] = a0 * 0.17677669529663687f;  // 1/sqrt(32)
        qkpL[1][h*64 + lane] = a1 * 0.17677669529663687f;
    }
    __syncthreads();

    {   // P3-P5: wave = (row, head): logits -> softmax -> agg, barrier-free
        int r = wv >> 3, h = wv & 7;
        float lg[2];
        #pragma unroll
        for (int jh = 0; jh < 2; ++jh) {
            int j = jh*64 + lane;
            float a = 0.f;
            #pragma unroll
            for (int ec = 0; ec < 16; ++ec) {
                float4 ev = *(float4*)&eds[r][j*68 + ec*4];
                float4 qa = *(float4*)&qkpL[r][h*64 + ec*4];  // uniform
                a += dot4(ev, qa);
            }
            lg[jh] = (mval[r][j] > 0.5f) ? a : SENT;
        }
        // softmax over 128 logits held as lg[0], lg[1] across 64 lanes
        float m = fmaxf(lg[0], lg[1]);
        #pragma unroll
        for (int off = 32; off >= 1; off >>= 1) m = fmaxf(m, __shfl_xor(m, off));
        float e0 = __expf(lg[0] - m), e1 = __expf(lg[1] - m);
        float s = e0 + e1;
        #pragma unroll
        for (int off = 32; off >= 1; off >>= 1) s += __shfl_xor(s, off);
        float inv = 1.0f / s;
        attL[r][h*132 + lane]      = e0 * inv;
        attL[r][h*132 + 64 + lane] = e1 * inv;
        // agg: lane = (jj = lane>>4 phase-major, ec = lane&15) -> 2-way free
        int jj = lane >> 4, ec = lane & 15;
        float4 acc = {0,0,0,0};
        #pragma unroll
        for (int js = 0; js < 32; ++js) {
            int j = js*4 + jj;
            float4 ev = *(float4*)&eds[r][j*68 + ec*4];
            float w = attL[r][h*132 + j];
            acc.x += w*ev.x; acc.y += w*ev.y; acc.z += w*ev.z; acc.w += w*ev.w;
        }
        #pragma unroll
        for (int off = 16; off <= 32; off <<= 1) {
            acc.x += __shfl_xor(acc.x, off); acc.y += __shfl_xor(acc.y, off);
            acc.z += __shfl_xor(acc.z, off); acc.w += __shfl_xor(acc.w, off);
        }
        if (jj == 0) *(float4*)&aggF[r][h*64 + ec*4] = acc;
    }
    __syncthreads();

    {   // P6: y[c] = vnode[c] + sum_e aggF[h(c)][e] * Wv[c][256+e]
        // wave handles c = ci*16 + wv for both rows; lane = e (coalesced)
        #pragma unroll 2
        for (int ci = 0; ci < 16; ++ci) {
            int c = ci*16 + wv;
            int h = c >> 5;
            float w = Wv[(size_t)c*320 + 256 + lane];
            float p0 = wred(w * aggF[0][h*64 + lane]);
            float p1 = wred(w * aggF[1][h*64 + lane]);
            if (lane == 0) {
                yL[0][c] = vnodeL[0][c] + p0;
                yL[1][c] = vnodeL[1][c] + p1;
            }
        }
    }
    __syncthreads();

    {   // P7: out[o] = bp[o] + Wp[o][:] . y ; full-row coalesced, both rows
        float4 ya = *(float4*)&yL[0][lane*4];
        float4 yb = *(float4*)&yL[1][lane*4];
        #pragma unroll 2
        for (int oi = 0; oi < 16; ++oi) {
            int o = oi*16 + wv;
            float4 w4 = *(const float4*)&Wp[(size_t)o*256 + lane*4];
            float d0 = wred(dot4(w4, ya));
            float d1 = wred(dot4(w4, yb));
            if (lane == 0) {
                float bb = bp[o];
                out[(size_t)rA*256 + o]       = d0 + bb;
                out[(size_t)(rA + 1)*256 + o] = d1 + bb;
            }
        }
    }
}

extern "C" void kernel_launch(void* const* d_in, const int* in_sizes, int n_in,
                              void* d_out, int out_size, void* d_ws, size_t ws_size,
                              hipStream_t stream) {
    (void)in_sizes; (void)n_in; (void)out_size; (void)d_ws; (void)ws_size;
    const float* x    = (const float*)d_in[0];
    // d_in[1] aux_x: unused by reference
    const int*   msk  = (const int*)d_in[2];
    const float* edge = (const float*)d_in[3];
    const float* Wq   = (const float*)d_in[4];
    const float* bq   = (const float*)d_in[5];
    const float* Wk   = (const float*)d_in[6];
    // d_in[7] bk: constant over j -> cancels in softmax, never needed
    const float* Wv   = (const float*)d_in[8];
    const float* bv   = (const float*)d_in[9];
    const float* Wp   = (const float*)d_in[10];
    const float* bp   = (const float*)d_in[11];
    float* out = (float*)d_out;

    fused_all<<<256, 1024, 0, stream>>>(x, msk, edge, Wq, bq, Wk, Wv, bv, Wp, bp, out);
}

// Round 6
// 37.237 us; speedup vs baseline: 2.1120x; 2.1120x over previous
//
#include <hip/hip_runtime.h>

#define SENT (-3.402823466e38f)

// ws layout (floats)
#define OFF_WQT   0            // [256k][256c]
#define OFF_WVNT  65536        // [256k][256c] (Wv node cols)
#define OFF_WPT   131072       // [256k][256c]
#define OFF_WKES  196608       // [256][64]  Wk edge cols * 1/sqrt(32), [c][e]
#define OFF_WVET  212992       // [64][256]  WvEt[e][c]

__device__ __forceinline__ float dot4(float4 a, float4 b) {
    return a.x*b.x + a.y*b.y + a.z*b.z + a.w*b.w;
}

// ---------------- K0: weight transposes / extractions (proven) ------------
__global__ void k0_setup(const float* __restrict__ Wq, const float* __restrict__ Wv,
                         const float* __restrict__ Wp, const float* __restrict__ Wk,
                         float* __restrict__ WqT, float* __restrict__ WvnT,
                         float* __restrict__ WpT, float* __restrict__ WkEs,
                         float* __restrict__ WvEt) {
    __shared__ float tile[32][33];
    int blk = blockIdx.x, tid = threadIdx.x;
    if (blk < 192) {
        int m = blk >> 6, t = blk & 63;
        int tr = t >> 3, tc = t & 7;
        const float* src; int ss; float* dst;
        if (m == 0)      { src = Wq; ss = 256; dst = WqT; }
        else if (m == 1) { src = Wv; ss = 320; dst = WvnT; }
        else             { src = Wp; ss = 256; dst = WpT; }
        #pragma unroll
        for (int i = 0; i < 4; ++i) {
            int rr = i*8 + (tid >> 5), kk = tid & 31;
            tile[rr][kk] = src[(size_t)(tr*32 + rr)*ss + tc*32 + kk];
        }
        __syncthreads();
        #pragma unroll
        for (int i = 0; i < 4; ++i) {
            int kk = i*8 + (tid >> 5), rr = tid & 31;
            dst[(size_t)(tc*32 + kk)*256 + tr*32 + rr] = tile[rr][kk];
        }
    } else if (blk < 208) {   // WvEt: [256c][64e] -> [64e][256c]
        int t = blk - 192;
        int tr = t >> 1, tc = t & 1;
        #pragma unroll
        for (int i = 0; i < 4; ++i) {
            int rr = i*8 + (tid >> 5), kk = tid & 31;
            tile[rr][kk] = Wv[(size_t)(tr*32 + rr)*320 + 256 + tc*32 + kk];
        }
        __syncthreads();
        #pragma unroll
        for (int i = 0; i < 4; ++i) {
            int kk = i*8 + (tid >> 5), rr = tid & 31;
            WvEt[(size_t)(tc*32 + kk)*256 + tr*32 + rr] = tile[rr][kk];
        }
    } else {                  // WkEs extract + scale
        int bb = blk - 208;
        int gid = bb*1024 + tid*4;
        int c = gid >> 6, e = gid & 63;
        const float s = 0.17677669529663687f;   // 1/sqrt(32)
        float4 v = *(const float4*)&Wk[(size_t)c*320 + 256 + e];
        v.x *= s; v.y *= s; v.z *= s; v.w *= s;
        *(float4*)&WkEs[c*64 + e] = v;
    }
}

// ---------------- Fused: 1 row per block, 512 blocks x 512 thr -------------
// All weight loops: wave kq owns k-range, lane = output col (coalesced W^T),
// x/y operands wave-uniform LDS broadcast, private accumulators, one LDS
// partial-combine. Attention: wave = head, in-wave softmax (no wred storms).
__global__ __launch_bounds__(512, 4)
void fused_row(const float* __restrict__ x, const int* __restrict__ msk,
               const float* __restrict__ edge,
               const float* __restrict__ WqT, const float* __restrict__ WvnT,
               const float* __restrict__ WpT, const float* __restrict__ WkEs,
               const float* __restrict__ WvEt,
               const float* __restrict__ bq, const float* __restrict__ bv,
               const float* __restrict__ bp, float* __restrict__ out) {
    __shared__ float eds[128*68];   // 34816B, stride 68 (16B-aligned rows)
    __shared__ float xL[256];
    __shared__ float qls[256];
    __shared__ float vnodeL[256];
    __shared__ float qkpL[512];     // [h][e]
    __shared__ float mval[128];
    __shared__ float attL[8*132];
    __shared__ float aggF[512];     // [h][e]
    __shared__ float yL[256];
    __shared__ float redA[8*256];   // P1 q partials; reused as P6/P7 partials
    __shared__ float redB[8*256];   // P1 v partials

    int tid = threadIdx.x;
    int wv = tid >> 6, lane = tid & 63;
    int row = blockIdx.x;

    // issue edge loads into regs; latency hides under P1's weight streaming
    float4 ef[4];
    {
        const float* eg = edge + (size_t)row * 8192;
        #pragma unroll
        for (int it = 0; it < 4; ++it)
            ef[it] = *(const float4*)(eg + (size_t)(tid + 512*it)*4);
    }
    if (tid < 256) xL[tid] = x[(size_t)row*256 + tid];
    else if (tid < 384) mval[tid-256] = (msk[(size_t)row*128 + (tid-256)] != 0) ? 1.0f : 0.0f;
    __syncthreads();

    {   // P1: q + vnode. wave kq=wv owns k-range [wv*32,+32); lane cc = col.
        #pragma unroll
        for (int cp = 0; cp < 4; ++cp) {
            int c = cp*64 + lane;
            const float* wq = WqT + (size_t)(wv*32)*256 + c;
            const float* wn = WvnT + (size_t)(wv*32)*256 + c;
            float aq = 0.f, av = 0.f;
            #pragma unroll 8
            for (int k = 0; k < 32; ++k) {
                float xv = xL[wv*32 + k];          // wave-uniform broadcast
                aq += wq[(size_t)k*256] * xv;
                av += wn[(size_t)k*256] * xv;
            }
            redA[wv*256 + c] = aq;
            redB[wv*256 + c] = av;
        }
        // stage edge regs -> LDS before the barrier
        #pragma unroll
        for (int it = 0; it < 4; ++it) {
            int fid = (tid + 512*it)*4;
            int j = fid >> 6, e = fid & 63;
            *(float4*)&eds[j*68 + e] = ef[it];
        }
    }
    __syncthreads();

    {   // P1-reduce: 512 threads cover q[256] (sel 0) and vnode[256] (sel 1)
        int sel = tid >> 8, c = tid & 255;
        const float* r = sel ? redB : redA;
        float s = 0.f;
        #pragma unroll
        for (int k2 = 0; k2 < 8; ++k2) s += r[k2*256 + c];
        if (sel == 0) qls[c] = s + bq[c];
        else          vnodeL[c] = s + bv[c];
    }
    __syncthreads();

    {   // P2: qkp[h][e] = sum_d q[h*32+d] * WkEs[h*32+d][e]; wave=h, lane=e
        const float* wk = WkEs + (size_t)(wv*32)*64 + lane;
        float a = 0.f;
        #pragma unroll 8
        for (int d = 0; d < 32; ++d)
            a += qls[wv*32 + d] * wk[(size_t)d*64];
        qkpL[wv*64 + lane] = a;     // scale baked into WkEs
    }
    __syncthreads();

    {   // P3-P5: wave = head. logits -> in-wave softmax -> agg. Barrier-free.
        int h = wv;
        float lg[2];
        #pragma unroll
        for (int jh = 0; jh < 2; ++jh) {
            int j = jh*64 + lane;
            float a = 0.f;
            #pragma unroll
            for (int ec = 0; ec < 16; ++ec) {
                float4 ev = *(float4*)&eds[j*68 + ec*4];
                float4 qa = *(float4*)&qkpL[h*64 + ec*4];   // uniform
                a += dot4(ev, qa);
            }
            lg[jh] = (mval[j] > 0.5f) ? a : SENT;
        }
        float m = fmaxf(lg[0], lg[1]);
        #pragma unroll
        for (int off = 32; off >= 1; off >>= 1) m = fmaxf(m, __shfl_xor(m, off));
        float e0 = __expf(lg[0] - m), e1 = __expf(lg[1] - m);
        float s = e0 + e1;
        #pragma unroll
        for (int off = 32; off >= 1; off >>= 1) s += __shfl_xor(s, off);
        float inv = 1.0f / s;
        attL[h*132 + lane]      = e0 * inv;
        attL[h*132 + 64 + lane] = e1 * inv;
        // agg over j: lane = (jj = lane>>4 phase-major, ec = lane&15)
        int jj = lane >> 4, ec = lane & 15;
        float4 acc = {0,0,0,0};
        #pragma unroll
        for (int js = 0; js < 32; ++js) {
            int j = js*4 + jj;
            float4 ev = *(float4*)&eds[j*68 + ec*4];
            float w = attL[h*132 + j];
            acc.x += w*ev.x; acc.y += w*ev.y; acc.z += w*ev.z; acc.w += w*ev.w;
        }
        #pragma unroll
        for (int off = 16; off <= 32; off <<= 1) {
            acc.x += __shfl_xor(acc.x, off); acc.y += __shfl_xor(acc.y, off);
            acc.z += __shfl_xor(acc.z, off); acc.w += __shfl_xor(acc.w, off);
        }
        if (jj == 0) *(float4*)&aggF[h*64 + ec*4] = acc;
    }
    __syncthreads();

    {   // P6: y[c] = vnode[c] + sum_e aggF[h(c)][e]*WvEt[e][c]; e split 2 ways
        int eh = tid >> 8, c = tid & 255;
        int h = c >> 5;
        const float* wv_col = WvEt + (size_t)(eh*32)*256 + c;
        float a = 0.f;
        #pragma unroll 8
        for (int e = 0; e < 32; ++e)
            a += aggF[h*64 + eh*32 + e] * wv_col[(size_t)e*256];
        redA[eh*256 + c] = a;
    }
    __syncthreads();
    if (tid < 256) yL[tid] = vnodeL[tid] + redA[tid] + redA[256 + tid];
    __syncthreads();

    {   // P7: out projection, same shape as P1
        #pragma unroll
        for (int cp = 0; cp < 4; ++cp) {
            int c = cp*64 + lane;
            const float* wp = WpT + (size_t)(wv*32)*256 + c;
            float a = 0.f;
            #pragma unroll 8
            for (int k = 0; k < 32; ++k)
                a += wp[(size_t)k*256] * yL[wv*32 + k];
            redB[wv*256 + c] = a;
        }
    }
    __syncthreads();
    if (tid < 256) {
        float s = bp[tid];
        #pragma unroll
        for (int k2 = 0; k2 < 8; ++k2) s += redB[k2*256 + tid];
        out[(size_t)row*256 + tid] = s;
    }
}

extern "C" void kernel_launch(void* const* d_in, const int* in_sizes, int n_in,
                              void* d_out, int out_size, void* d_ws, size_t ws_size,
                              hipStream_t stream) {
    (void)in_sizes; (void)n_in; (void)out_size; (void)ws_size;
    const float* x    = (const float*)d_in[0];
    // d_in[1] aux_x: unused by reference
    const int*   msk  = (const int*)d_in[2];
    const float* edge = (const float*)d_in[3];
    const float* Wq   = (const float*)d_in[4];
    const float* bq   = (const float*)d_in[5];
    const float* Wk   = (const float*)d_in[6];
    // d_in[7] bk: constant over j -> cancels in softmax
    const float* Wv   = (const float*)d_in[8];
    const float* bv   = (const float*)d_in[9];
    const float* Wp   = (const float*)d_in[10];
    const float* bp   = (const float*)d_in[11];
    float* out = (float*)d_out;
    float* ws  = (float*)d_ws;

    float* WqT  = ws + OFF_WQT;
    float* WvnT = ws + OFF_WVNT;
    float* WpT  = ws + OFF_WPT;
    float* WkEs = ws + OFF_WKES;
    float* WvEt = ws + OFF_WVET;

    k0_setup<<<224, 256, 0, stream>>>(Wq, Wv, Wp, Wk, WqT, WvnT, WpT, WkEs, WvEt);
    fused_row<<<512, 512, 0, stream>>>(x, msk, edge, WqT, WvnT, WpT, WkEs, WvEt,
                                       bq, bv, bp, out);
}

// Round 7
// 31.869 us; speedup vs baseline: 2.4677x; 1.1684x over previous
//
#include <hip/hip_runtime.h>

#define SENT (-3.402823466e38f)

// ws layout (floats)
#define OFF_WQT   0            // [256k][256c]
#define OFF_WVNT  65536        // [256k][256c] (Wv node cols)
#define OFF_WPT   131072       // [256k][256o]
#define OFF_WKES  196608       // [256c][64e]  Wk edge cols * 1/sqrt(32)
#define OFF_WVET  212992       // [64e][256c]
#define OFF_QKP   229376       // [512r][512he]; k2 overwrites with agg (safe: block reads its own row first)
#define OFF_VNODE 491520       // [512r][256c]

__device__ __forceinline__ float dot4(float4 a, float4 b) {
    return a.x*b.x + a.y*b.y + a.z*b.z + a.w*b.w;
}

// ---------------- K0: weight transposes / extractions (proven) ------------
__global__ void k0_setup(const float* __restrict__ Wq, const float* __restrict__ Wv,
                         const float* __restrict__ Wp, const float* __restrict__ Wk,
                         float* __restrict__ WqT, float* __restrict__ WvnT,
                         float* __restrict__ WpT, float* __restrict__ WkEs,
                         float* __restrict__ WvEt) {
    __shared__ float tile[32][33];
    int blk = blockIdx.x, tid = threadIdx.x;
    if (blk < 192) {
        int m = blk >> 6, t = blk & 63;
        int tr = t >> 3, tc = t & 7;
        const float* src; int ss; float* dst;
        if (m == 0)      { src = Wq; ss = 256; dst = WqT; }
        else if (m == 1) { src = Wv; ss = 320; dst = WvnT; }
        else             { src = Wp; ss = 256; dst = WpT; }
        #pragma unroll
        for (int i = 0; i < 4; ++i) {
            int rr = i*8 + (tid >> 5), kk = tid & 31;
            tile[rr][kk] = src[(size_t)(tr*32 + rr)*ss + tc*32 + kk];
        }
        __syncthreads();
        #pragma unroll
        for (int i = 0; i < 4; ++i) {
            int kk = i*8 + (tid >> 5), rr = tid & 31;
            dst[(size_t)(tc*32 + kk)*256 + tr*32 + rr] = tile[rr][kk];
        }
    } else if (blk < 208) {   // WvEt: [256c][64e] -> [64e][256c]
        int t = blk - 192;
        int tr = t >> 1, tc = t & 1;
        #pragma unroll
        for (int i = 0; i < 4; ++i) {
            int rr = i*8 + (tid >> 5), kk = tid & 31;
            tile[rr][kk] = Wv[(size_t)(tr*32 + rr)*320 + 256 + tc*32 + kk];
        }
        __syncthreads();
        #pragma unroll
        for (int i = 0; i < 4; ++i) {
            int kk = i*8 + (tid >> 5), rr = tid & 31;
            WvEt[(size_t)(tc*32 + kk)*256 + tr*32 + rr] = tile[rr][kk];
        }
    } else {                  // WkEs extract + scale
        int bb = blk - 208;
        int gid = bb*1024 + tid*4;
        int c = gid >> 6, e = gid & 63;
        const float s = 0.17677669529663687f;   // 1/sqrt(32)
        float4 v = *(const float4*)&Wk[(size_t)c*320 + 256 + e];
        v.x *= s; v.y *= s; v.z *= s; v.w *= s;
        *(float4*)&WkEs[c*64 + e] = v;
    }
}

// ---------------- K1: batched q -> qkp, vnode ------------------------------
// grid 512: rb = blk>>2 (4 rows), cb = blk&3 (64 cols = heads {2cb,2cb+1}).
__global__ __launch_bounds__(512, 4)
void k1_proj(const float* __restrict__ x, const float* __restrict__ WqT,
             const float* __restrict__ WvnT, const float* __restrict__ WkEs,
             const float* __restrict__ bq, const float* __restrict__ bv,
             float* __restrict__ vnode, float* __restrict__ qkp) {
    __shared__ float xL[4][256];
    __shared__ float redq[8][256];   // [kq][r*64+cc]
    __shared__ float redv[8][256];
    __shared__ float qls[4][64];
    int tid = threadIdx.x;
    int wv = tid >> 6, lane = tid & 63;
    int rb = blockIdx.x >> 2, cb = blockIdx.x & 3;
    int r0 = rb*4, c0 = cb*64, h0 = cb*2;

    {   // stage x rows (coalesced float2)
        int idx = tid*2, r = idx >> 8, k = idx & 255;
        float2 v = *(const float2*)&x[(size_t)(r0 + r)*256 + k];
        xL[r][k] = v.x; xL[r][k+1] = v.y;
    }
    __syncthreads();

    {   // P1: wave = kq (32 k's), lane = cc. Coalesced 256B weight streams.
        int c = c0 + lane;
        const float* wq = WqT + (size_t)(wv*32)*256 + c;
        const float* wn = WvnT + (size_t)(wv*32)*256 + c;
        float aq[4] = {0,0,0,0}, av[4] = {0,0,0,0};
        #pragma unroll 8
        for (int k = 0; k < 32; ++k) {
            float q4 = wq[(size_t)k*256];
            float n4 = wn[(size_t)k*256];
            #pragma unroll
            for (int r = 0; r < 4; ++r) {
                float xv = xL[r][wv*32 + k];   // wave-uniform broadcast
                aq[r] += xv * q4;
                av[r] += xv * n4;
            }
        }
        #pragma unroll
        for (int r = 0; r < 4; ++r) {
            redq[wv][r*64 + lane] = aq[r];
            redv[wv][r*64 + lane] = av[r];
        }
    }
    __syncthreads();

    {   // reduce: tid = (mat, r, cc): 2*4*64 = 512
        int mat = tid >> 8, rr = (tid >> 6) & 3, cc = lane;
        const float (*red)[256] = mat ? redv : redq;
        float s = 0.f;
        #pragma unroll
        for (int kq = 0; kq < 8; ++kq) s += red[kq][rr*64 + cc];
        if (mat == 0) qls[rr][cc] = s + bq[c0 + cc];
        else vnode[(size_t)(r0 + rr)*256 + c0 + cc] = s + bv[c0 + cc];
    }
    __syncthreads();

    {   // P2: qkp[r][h][e]; thread = (rr, hl, e). WkEs coalesced 256B.
        int rr = tid >> 7, hl = (tid >> 6) & 1, e = lane;
        const float* wk = WkEs + (size_t)((h0 + hl)*32)*64 + e;
        float a = 0.f;
        #pragma unroll 8
        for (int d = 0; d < 32; ++d)
            a += qls[rr][hl*32 + d] * wk[(size_t)d*64];
        qkp[(size_t)(r0 + rr)*512 + (h0 + hl)*64 + e] = a;
    }
}

// ---------------- K2: per-row attention -> agg -----------------------------
// grid 512, 512 thr, 37.4KB LDS -> 4 blocks/CU. One barrier.
__global__ __launch_bounds__(512, 4)
void k2_attn(const float* __restrict__ edge, const int* __restrict__ msk,
             const float* __restrict__ qkp, float* __restrict__ agg) {
    __shared__ float eds[128*68];   // stride 68: 16B-aligned rows
    __shared__ float qkpL[512];
    __shared__ float mval[128];

    int tid = threadIdx.x;
    int wv = tid >> 6, lane = tid & 63;
    int row = blockIdx.x;

    float4 ef[4];
    {
        const float* eg = edge + (size_t)row * 8192;
        #pragma unroll
        for (int it = 0; it < 4; ++it)
            ef[it] = *(const float4*)(eg + (size_t)(tid + 512*it)*4);
    }
    qkpL[tid] = qkp[(size_t)row*512 + tid];
    if (tid < 128) mval[tid] = (msk[(size_t)row*128 + tid] != 0) ? 1.0f : 0.0f;
    #pragma unroll
    for (int it = 0; it < 4; ++it) {
        int fid = (tid + 512*it)*4;
        int j = fid >> 6, e = fid & 63;
        *(float4*)&eds[j*68 + e] = ef[it];
    }
    __syncthreads();

    int h = wv;
    float lg0, lg1;
    {
        float a0 = 0.f, a1 = 0.f;
        #pragma unroll
        for (int ec = 0; ec < 16; ++ec) {
            float4 qa = *(float4*)&qkpL[h*64 + ec*4];            // uniform
            float4 e0v = *(float4*)&eds[lane*68 + ec*4];
            float4 e1v = *(float4*)&eds[(64 + lane)*68 + ec*4];
            a0 += dot4(e0v, qa); a1 += dot4(e1v, qa);
        }
        lg0 = (mval[lane] > 0.5f) ? a0 : SENT;
        lg1 = (mval[64 + lane] > 0.5f) ? a1 : SENT;
    }
    // in-wave softmax over the 128 logits
    float m = fmaxf(lg0, lg1);
    #pragma unroll
    for (int off = 32; off >= 1; off >>= 1) m = fmaxf(m, __shfl_xor(m, off));
    float e0 = __expf(lg0 - m), e1 = __expf(lg1 - m);
    float s = e0 + e1;
    #pragma unroll
    for (int off = 32; off >= 1; off >>= 1) s += __shfl_xor(s, off);
    float inv = 1.0f / s;
    float att0 = e0 * inv;     // att for j = lane
    float att1 = e1 * inv;     // att for j = 64 + lane

    {   // agg[h][e] = sum_j att[j]*edge[j][e]; lane = (jj = lane>>4, ec = lane&15)
        int jj = lane >> 4, ec = lane & 15;
        float4 acc = {0,0,0,0};
        #pragma unroll
        for (int js = 0; js < 16; ++js) {
            int j = js*4 + jj;
            float w = __shfl(att0, j);
            float4 ev = *(float4*)&eds[j*68 + ec*4];
            acc.x += w*ev.x; acc.y += w*ev.y; acc.z += w*ev.z; acc.w += w*ev.w;
        }
        #pragma unroll
        for (int js = 0; js < 16; ++js) {
            int j = js*4 + jj;
            float w = __shfl(att1, j);
            float4 ev = *(float4*)&eds[(64 + j)*68 + ec*4];
            acc.x += w*ev.x; acc.y += w*ev.y; acc.z += w*ev.z; acc.w += w*ev.w;
        }
        #pragma unroll
        for (int off = 16; off <= 32; off <<= 1) {
            acc.x += __shfl_xor(acc.x, off); acc.y += __shfl_xor(acc.y, off);
            acc.z += __shfl_xor(acc.z, off); acc.w += __shfl_xor(acc.w, off);
        }
        if (jj == 0)
            *(float4*)&agg[(size_t)row*512 + h*64 + ec*4] = acc;
    }
}

// ---------------- K3: y = vnode + agg@WvEt^T, out = y@WpT + bp -------------
// grid 512: rb = blk>>2 (4 rows), cb = blk&3 (64 out-cols).
__global__ __launch_bounds__(512, 4)
void k3_out(const float* __restrict__ vnode, const float* __restrict__ agg,
            const float* __restrict__ WvEt, const float* __restrict__ WpT,
            const float* __restrict__ bp, float* __restrict__ out) {
    __shared__ float aggL[4][512];
    __shared__ float yL[4][256];
    __shared__ float redP[8][256];   // [kq][r*64+oc]
    int tid = threadIdx.x;
    int wv = tid >> 6, lane = tid & 63;
    int rb = blockIdx.x >> 2, cb = blockIdx.x & 3;
    int r0 = rb*4, o0 = cb*64;

    {   // stage agg (float4 coalesced)
        int idx = tid*4, r = idx >> 9, he = idx & 511;
        *(float4*)&aggL[r][he] = *(const float4*)&agg[(size_t)(r0 + r)*512 + he];
    }
    __syncthreads();

    {   // phase A: y for rows {rA, rA+2}, c = tid&255. WvEt coalesced 256B.
        int c = tid & 255, rA = tid >> 8;
        int hbase = (c >> 5)*64;
        const float* wv_ = WvEt + c;
        float y0 = vnode[(size_t)(r0 + rA)*256 + c];
        float y1 = vnode[(size_t)(r0 + rA + 2)*256 + c];
        #pragma unroll 8
        for (int e = 0; e < 64; ++e) {
            float w = wv_[(size_t)e*256];
            y0 += aggL[rA][hbase + e] * w;
            y1 += aggL[rA + 2][hbase + e] * w;
        }
        yL[rA][c] = y0; yL[rA + 2][c] = y1;
    }
    __syncthreads();

    {   // phase B: wave = kq, lane = oc. WpT coalesced 256B.
        int o = o0 + lane;
        const float* wp = WpT + (size_t)(wv*32)*256 + o;
        float a[4] = {0,0,0,0};
        #pragma unroll 8
        for (int k = 0; k < 32; ++k) {
            float w = wp[(size_t)k*256];
            #pragma unroll
            for (int r = 0; r < 4; ++r)
                a[r] += yL[r][wv*32 + k] * w;   // wave-uniform broadcast
        }
        #pragma unroll
        for (int r = 0; r < 4; ++r) redP[wv][r*64 + lane] = a[r];
    }
    __syncthreads();

    if (tid < 256) {
        int r = tid >> 6, oc = tid & 63;
        float s = bp[o0 + oc];
        #pragma unroll
        for (int kq = 0; kq < 8; ++kq) s += redP[kq][r*64 + oc];
        out[(size_t)(r0 + r)*256 + o0 + oc] = s;
    }
}

extern "C" void kernel_launch(void* const* d_in, const int* in_sizes, int n_in,
                              void* d_out, int out_size, void* d_ws, size_t ws_size,
                              hipStream_t stream) {
    (void)in_sizes; (void)n_in; (void)out_size; (void)ws_size;
    const float* x    = (const float*)d_in[0];
    // d_in[1] aux_x: unused by reference
    const int*   msk  = (const int*)d_in[2];
    const float* edge = (const float*)d_in[3];
    const float* Wq   = (const float*)d_in[4];
    const float* bq   = (const float*)d_in[5];
    const float* Wk   = (const float*)d_in[6];
    // d_in[7] bk: constant over j -> cancels in softmax
    const float* Wv   = (const float*)d_in[8];
    const float* bv   = (const float*)d_in[9];
    const float* Wp   = (const float*)d_in[10];
    const float* bp   = (const float*)d_in[11];
    float* out = (float*)d_out;
    float* ws  = (float*)d_ws;

    float* WqT   = ws + OFF_WQT;
    float* WvnT  = ws + OFF_WVNT;
    float* WpT   = ws + OFF_WPT;
    float* WkEs  = ws + OFF_WKES;
    float* WvEt  = ws + OFF_WVET;
    float* qkp   = ws + OFF_QKP;     // k2 overwrites this buffer with agg
    float* vnode = ws + OFF_VNODE;

    k0_setup<<<224, 256, 0, stream>>>(Wq, Wv, Wp, Wk, WqT, WvnT, WpT, WkEs, WvEt);
    k1_proj<<<512, 512, 0, stream>>>(x, WqT, WvnT, WkEs, bq, bv, vnode, qkp);
    k2_attn<<<512, 512, 0, stream>>>(edge, msk, qkp, qkp);
    k3_out<<<512, 512, 0, stream>>>(vnode, qkp, WvEt, WpT, bp, out);
}